// Round 1
// baseline (627.181 us; speedup 1.0000x reference)
//
#include <hip/hip_runtime.h>

#define MROWS 8192
#define NCOLS 128
#define LDT 88          // LDS row stride in bf16 elements (176 B: 16B-aligned, 2-way banks)
#define KSTEP 64
#define SPLITK 8

using f32x4  = __attribute__((ext_vector_type(4))) float;
using bf16x8 = __attribute__((ext_vector_type(8))) short;
using u32x4  = __attribute__((ext_vector_type(4))) unsigned int;
using u32x2  = __attribute__((ext_vector_type(2))) unsigned int;

__device__ __forceinline__ unsigned short f2bf(float f) {
    unsigned int u = __float_as_uint(f);
    u += 0x7fffu + ((u >> 16) & 1u);   // RNE
    return (unsigned short)(u >> 16);
}
__device__ __forceinline__ unsigned int pk2(float a, float b) {
    return (unsigned int)f2bf(a) | ((unsigned int)f2bf(b) << 16);
}

// C[M,128] = A[M,Kdim](fp32) @ B[Kdim,128] where B is stored transposed bf16: Bt[c][k].
// OUTMODE: 0 = fp32 partials transposed  Pt[s][c][r]   (float4 stores)
//          1 = fp32 partials row-major   P[s][r][c]    (scalar stores, 64B segments)
//          2 = bf16 direct transposed    Tt[c][r]      (SPLITK must be 1)
template <int OUTMODE>
__global__ __launch_bounds__(256, 2) void gemm_kernel(
    const float* __restrict__ A,
    const unsigned short* __restrict__ Bt,
    void* __restrict__ out,
    int Kdim, int KC, int ldb)
{
    __shared__ __align__(16) unsigned short As[128 * LDT];
    __shared__ __align__(16) unsigned short Bs[128 * LDT];

    const int tid  = threadIdx.x;
    const int wave = tid >> 6;
    const int lane = tid & 63;
    const int lrow = lane & 15;
    const int lq   = lane >> 4;          // quad 0..3
    const int mq   = (wave & 1) * 64;
    const int nq   = (wave >> 1) * 64;
    const int m0   = blockIdx.x * 128;
    const int s    = blockIdx.y;
    const int kbase = s * KC;
    const int iters = KC >> 6;           // KC / KSTEP

    const int trow = tid >> 3;           // 0..31 (row within 32-row pass)
    const int tk   = (tid & 7) * 8;      // k element offset 0..56

    f32x4 areg[4][2];
    u32x4 breg[4];

    const float*          Aptr = A  + (size_t)(m0 + trow) * Kdim + tk;
    const unsigned short* Bptr = Bt + (size_t)trow * ldb + tk;

    auto load_stage = [&](int k0) {
#pragma unroll
        for (int p = 0; p < 4; ++p) {
            const float* ap = Aptr + (size_t)(p * 32) * Kdim + k0;
            areg[p][0] = *(const f32x4*)(ap);
            areg[p][1] = *(const f32x4*)(ap + 4);
            breg[p]    = *(const u32x4*)(Bptr + (size_t)(p * 32) * ldb + k0);
        }
    };
    auto store_stage = [&]() {
#pragma unroll
        for (int p = 0; p < 4; ++p) {
            int row = trow + p * 32;
            u32x4 av;
            av.x = pk2(areg[p][0].x, areg[p][0].y);
            av.y = pk2(areg[p][0].z, areg[p][0].w);
            av.z = pk2(areg[p][1].x, areg[p][1].y);
            av.w = pk2(areg[p][1].z, areg[p][1].w);
            *(u32x4*)&As[row * LDT + tk] = av;
            *(u32x4*)&Bs[row * LDT + tk] = breg[p];
        }
    };

    f32x4 acc[4][4];
#pragma unroll
    for (int i = 0; i < 4; ++i)
#pragma unroll
        for (int j = 0; j < 4; ++j)
            acc[i][j] = {0.f, 0.f, 0.f, 0.f};

    load_stage(kbase);
    for (int it = 0; it < iters; ++it) {
        __syncthreads();
        store_stage();
        __syncthreads();
        if (it + 1 < iters) load_stage(kbase + (it + 1) * KSTEP);   // prefetch overlaps MFMA
#pragma unroll
        for (int kk = 0; kk < 2; ++kk) {
            const int ko = kk * 32 + lq * 8;
            bf16x8 afr[4], bfr[4];
#pragma unroll
            for (int mt = 0; mt < 4; ++mt)
                afr[mt] = *(bf16x8*)&As[(mq + mt * 16 + lrow) * LDT + ko];
#pragma unroll
            for (int nt = 0; nt < 4; ++nt)
                bfr[nt] = *(bf16x8*)&Bs[(nq + nt * 16 + lrow) * LDT + ko];
#pragma unroll
            for (int mt = 0; mt < 4; ++mt)
#pragma unroll
                for (int nt = 0; nt < 4; ++nt)
                    acc[mt][nt] = __builtin_amdgcn_mfma_f32_16x16x32_bf16(
                        afr[mt], bfr[nt], acc[mt][nt], 0, 0, 0);
        }
    }

    if (OUTMODE == 0) {
        float* P = (float*)out + (size_t)s * (MROWS * NCOLS);
#pragma unroll
        for (int mt = 0; mt < 4; ++mt) {
            int r = m0 + mq + mt * 16 + lq * 4;
#pragma unroll
            for (int nt = 0; nt < 4; ++nt) {
                int c = nq + nt * 16 + lrow;
                *(f32x4*)&P[(size_t)c * MROWS + r] = acc[mt][nt];
            }
        }
    } else if (OUTMODE == 1) {
        float* P = (float*)out + (size_t)s * (MROWS * NCOLS);
#pragma unroll
        for (int mt = 0; mt < 4; ++mt) {
            int r = m0 + mq + mt * 16 + lq * 4;
#pragma unroll
            for (int nt = 0; nt < 4; ++nt) {
                int c = nq + nt * 16 + lrow;
#pragma unroll
                for (int e = 0; e < 4; ++e)
                    P[(size_t)(r + e) * NCOLS + c] = acc[mt][nt][e];
            }
        }
    } else {
        unsigned short* Tt = (unsigned short*)out;
#pragma unroll
        for (int mt = 0; mt < 4; ++mt) {
            int r = m0 + mq + mt * 16 + lq * 4;
#pragma unroll
            for (int nt = 0; nt < 4; ++nt) {
                int c = nq + nt * 16 + lrow;
                u32x2 v;
                v.x = pk2(acc[mt][nt][0], acc[mt][nt][1]);
                v.y = pk2(acc[mt][nt][2], acc[mt][nt][3]);
                *(u32x2*)&Tt[(size_t)c * MROWS + r] = v;
            }
        }
    }
}

// Wt[c][k] = bf16(W[k][c]) : 256x128 fp32 -> transposed bf16
__global__ void convert_w(const float* __restrict__ W, unsigned short* __restrict__ Wt) {
    int idx = blockIdx.x * 256 + threadIdx.x;   // 32768 total
    int k = idx >> 7, c = idx & 127;
    Wt[c * 256 + k] = f2bf(W[idx]);
}

// Rt[c][r] = bf16( filt[r] * sum_s Pt[s][c][r] )
__global__ void reduce2(const float* __restrict__ P, const float* __restrict__ filt,
                        unsigned short* __restrict__ Rt) {
    int idx4 = (blockIdx.x * 256 + threadIdx.x) * 4;
    f32x4 sum = {0.f, 0.f, 0.f, 0.f};
#pragma unroll
    for (int s = 0; s < SPLITK; ++s)
        sum += *(const f32x4*)&P[(size_t)s * (MROWS * NCOLS) + idx4];
    int r = idx4 & (MROWS - 1);
    f32x4 fl = *(const f32x4*)&filt[r];
    sum *= fl;
    u32x2 v;
    v.x = pk2(sum.x, sum.y);
    v.y = pk2(sum.z, sum.w);
    *(u32x2*)&Rt[idx4] = v;
}

// out[r][c] = sum_s P[s][r][c]   (row-major partials, fully coalesced)
__global__ void reduce3(const float* __restrict__ P, float* __restrict__ outp) {
    int idx4 = (blockIdx.x * 256 + threadIdx.x) * 4;
    f32x4 sum = {0.f, 0.f, 0.f, 0.f};
#pragma unroll
    for (int s = 0; s < SPLITK; ++s)
        sum += *(const f32x4*)&P[(size_t)s * (MROWS * NCOLS) + idx4];
    *(f32x4*)&outp[idx4] = sum;
}

extern "C" void kernel_launch(void* const* d_in, const int* in_sizes, int n_in,
                              void* d_out, int out_size, void* d_ws, size_t ws_size,
                              hipStream_t stream) {
    const float* features     = (const float*)d_in[0];
    const float* wavelets     = (const float*)d_in[1];
    const float* wavelets_inv = (const float*)d_in[2];
    const float* W            = (const float*)d_in[3];
    const float* filt         = (const float*)d_in[4];
    float* outp = (float*)d_out;

    char* ws = (char*)d_ws;
    float*          P  = (float*)ws;                                        // 32 MB partials (shared by GEMM2/GEMM3)
    unsigned short* Tt = (unsigned short*)(ws + (size_t)32 * 1024 * 1024);  // 2 MB  Tt[c][r]
    unsigned short* Rt = (unsigned short*)(ws + (size_t)34 * 1024 * 1024);  // 2 MB  Rt[c][r]
    unsigned short* Wt = (unsigned short*)(ws + (size_t)36 * 1024 * 1024);  // 64 KB Wt[c][k]

    // 1) W -> Wt (bf16, transposed)
    convert_w<<<128, 256, 0, stream>>>(W, Wt);
    // 2) Tt = (features @ W)^T   (K=256, no split-K, direct bf16 transposed output)
    gemm_kernel<2><<<dim3(64, 1), 256, 0, stream>>>(features, Wt, (void*)Tt, 256, 256, 256);
    // 3) Pt[s] = partial (wavelets_inv @ T)^T   (split-K=8)
    gemm_kernel<0><<<dim3(64, 8), 256, 0, stream>>>(wavelets_inv, Tt, (void*)P, 8192, 1024, 8192);
    // 4) Rt = bf16(filt ⊙ reduce(Pt))  (transposed)
    reduce2<<<1024, 256, 0, stream>>>(P, filt, Rt);
    // 5) P[s] = partial wavelets @ R   (row-major partials)
    gemm_kernel<1><<<dim3(64, 8), 256, 0, stream>>>(wavelets, Rt, (void*)P, 8192, 1024, 8192);
    // 6) out = reduce(P)
    reduce3<<<1024, 256, 0, stream>>>(P, outp);
}